// Round 3
// baseline (581.034 us; speedup 1.0000x reference)
//
#include <hip/hip_runtime.h>
#include <stdint.h>

#define K_DIM 512
#define N_OUT 512
#define BM 256   // block rows (4 waves stacked in M, 64 rows each)
#define BN 128   // block cols (each wave covers all 128 via ni=0..7)

typedef __bf16 bf16x8 __attribute__((ext_vector_type(8)));
typedef float f32x4 __attribute__((ext_vector_type(4)));
typedef unsigned short ushort8 __attribute__((ext_vector_type(8)));

__device__ inline unsigned short f2bf(float f) {
  unsigned u = __float_as_uint(f);
  u += 0x7fffu + ((u >> 16) & 1u);
  return (unsigned short)(u >> 16);
}

// ---------------- phase 1: fp32 -> bf16 conversion into workspace ----------------
__global__ __launch_bounds__(256) void cvt_bf16_kernel(const float* __restrict__ src,
                                                       unsigned short* __restrict__ dst,
                                                       int n8) {
  int i = blockIdx.x * 256 + threadIdx.x;
  if (i >= n8) return;
  const float4* s = (const float4*)src + (size_t)i * 2;
  float4 a = s[0], c = s[1];
  ushort8 o;
  o[0] = f2bf(a.x); o[1] = f2bf(a.y); o[2] = f2bf(a.z); o[3] = f2bf(a.w);
  o[4] = f2bf(c.x); o[5] = f2bf(c.y); o[6] = f2bf(c.z); o[7] = f2bf(c.w);
  *(ushort8*)(dst + (size_t)i * 8) = o;
}

// ---------------- phase 2: zero-LDS, zero-barrier register GEMM ------------------
// A-fragments stream from global bf16 x (L3-resident, 102 MB, read 4x).
// B-fragments stream from global bf16 W (512 KB, L2-resident on every XCD).
// No __shared__, no __syncthreads => compiler free to pipeline loads across
// the K-loop with fine-grained vmcnt, no barrier drain.
__global__ __launch_bounds__(256, 2) void gemm_reg_kernel(
    const unsigned short* __restrict__ xb, const unsigned short* __restrict__ wb,
    const float* __restrict__ b, float* __restrict__ out, int M) {
  const int tid = threadIdx.x;
  const int lane = tid & 63;
  const int quad = lane >> 4;
  const int l16 = lane & 15;
  const int waveId = tid >> 6;

  const int blockM = blockIdx.y * BM;
  const int blockN = blockIdx.x * BN;
  const int wrow = blockM + waveId * 64;  // this wave's 64-row strip

  // A-fragment base pointers (clamped rows for the M tail; masked at store)
  const unsigned short* aptr[4];
#pragma unroll
  for (int mi = 0; mi < 4; ++mi) {
    int r = wrow + mi * 16 + l16;
    if (r > M - 1) r = M - 1;
    aptr[mi] = xb + (size_t)r * K_DIM + quad * 8;
  }
  // B-fragment base pointers
  const unsigned short* bptr[8];
#pragma unroll
  for (int ni = 0; ni < 8; ++ni)
    bptr[ni] = wb + (size_t)(blockN + ni * 16 + l16) * K_DIM + quad * 8;

  f32x4 acc[4][8] = {};

#pragma unroll 4
  for (int s = 0; s < K_DIM / 32; ++s) {  // 16 K-steps of 32
    bf16x8 af[4], bf[8];
#pragma unroll
    for (int mi = 0; mi < 4; ++mi)
      af[mi] = *(const bf16x8*)(aptr[mi] + s * 32);
#pragma unroll
    for (int ni = 0; ni < 8; ++ni)
      bf[ni] = *(const bf16x8*)(bptr[ni] + s * 32);
#pragma unroll
    for (int mi = 0; mi < 4; ++mi)
#pragma unroll
      for (int ni = 0; ni < 8; ++ni)
        acc[mi][ni] = __builtin_amdgcn_mfma_f32_16x16x32_bf16(af[mi], bf[ni], acc[mi][ni], 0, 0, 0);
  }

  // epilogue: bias + relu; C/D layout col=lane&15, row=quad*4+reg (verified r1/r2)
#pragma unroll
  for (int ni = 0; ni < 8; ++ni) {
    int gcol = blockN + ni * 16 + l16;
    float bias = b[gcol];
#pragma unroll
    for (int mi = 0; mi < 4; ++mi) {
#pragma unroll
      for (int r = 0; r < 4; ++r) {
        int grow = wrow + mi * 16 + quad * 4 + r;
        if (grow < M) {
          float v = acc[mi][ni][r] + bias;
          out[(size_t)grow * N_OUT + gcol] = v > 0.f ? v : 0.f;
        }
      }
    }
  }
}

// out[col[e], 0] += x[e, 0]
__global__ void scatter_kernel(const float* __restrict__ x,
                               const int* __restrict__ ei,
                               float* __restrict__ out, int E) {
  int e = blockIdx.x * 256 + threadIdx.x;
  if (e < E) {
    int c = ei[E + e];
    atomicAdd(out + (size_t)c * N_OUT, x[(size_t)e * K_DIM]);
  }
}

extern "C" void kernel_launch(void* const* d_in, const int* in_sizes, int n_in,
                              void* d_out, int out_size, void* d_ws, size_t ws_size,
                              hipStream_t stream) {
  const float* x = (const float*)d_in[0];
  const int* ei = (const int*)d_in[1];
  const float* W = (const float*)d_in[2];
  const float* b = (const float*)d_in[3];
  float* out = (float*)d_out;

  int M = in_sizes[0] / K_DIM;  // 100000
  int E = in_sizes[1] / 2;      // 100000

  size_t x_elems = (size_t)M * K_DIM;      // 51,200,000
  size_t w_elems = (size_t)N_OUT * K_DIM;  // 262,144

  unsigned short* xb = (unsigned short*)d_ws;
  unsigned short* wb = xb + x_elems;

  int n8x = (int)(x_elems / 8);
  int n8w = (int)(w_elems / 8);
  cvt_bf16_kernel<<<(n8x + 255) / 256, 256, 0, stream>>>(x, xb, n8x);
  cvt_bf16_kernel<<<(n8w + 255) / 256, 256, 0, stream>>>(W, wb, n8w);

  dim3 grid(N_OUT / BN, (M + BM - 1) / BM);  // (4, 391)
  gemm_reg_kernel<<<grid, 256, 0, stream>>>(xb, wb, b, out, M);

  scatter_kernel<<<(E + 255) / 256, 256, 0, stream>>>(x, ei, out, E);
}